// Round 1
// baseline (1836.757 us; speedup 1.0000x reference)
//
#include <hip/hip_runtime.h>

#define NROWS 16384
#define KCB   16384
#define DIM   64
#define BM    64
#define BK    64
#define KSPLIT 4
#define KCHUNK (KCB / KSPLIT)

__global__ __launch_bounds__(256) void quant_partial(
    const float* __restrict__ x_re, const float* __restrict__ x_im,
    const float* __restrict__ cb_re, const float* __restrict__ cb_im,
    float* __restrict__ ws_mag, int* __restrict__ ws_idx)
{
    __shared__ float xsr[DIM][BM];
    __shared__ float xsi[DIM][BM];
    __shared__ float csr[DIM][BK];
    __shared__ float csi[DIM][BK];

    const int tid  = threadIdx.x;
    const int row0 = blockIdx.x * BM;
    const int kseg = blockIdx.y;
    const int kbeg = kseg * KCHUNK;

    // ---- stage x tile, transposed to [d][row] ----
    {
        const int r = tid & 63;
        const int q = tid >> 6;  // 0..3
        const float4* pr = reinterpret_cast<const float4*>(&x_re[(size_t)(row0 + r) * DIM + q * 16]);
        const float4* pi = reinterpret_cast<const float4*>(&x_im[(size_t)(row0 + r) * DIM + q * 16]);
#pragma unroll
        for (int j = 0; j < 4; ++j) {
            float4 vr = pr[j];
            float4 vi = pi[j];
            int d = q * 16 + j * 4;
            xsr[d + 0][r] = vr.x; xsr[d + 1][r] = vr.y; xsr[d + 2][r] = vr.z; xsr[d + 3][r] = vr.w;
            xsi[d + 0][r] = vi.x; xsi[d + 1][r] = vi.y; xsi[d + 2][r] = vi.z; xsi[d + 3][r] = vi.w;
        }
    }

    const int tx = tid & 15;   // col group (4 cols)
    const int ty = tid >> 4;   // row group (4 rows), 0..15

    float best_m[4];
    int   best_i[4];
#pragma unroll
    for (int i = 0; i < 4; ++i) { best_m[i] = -1.0f; best_i[i] = 0; }

    for (int k0 = kbeg; k0 < kbeg + KCHUNK; k0 += BK) {
        __syncthreads();
        // ---- stage codebook tile, transposed to [d][col] ----
        {
            const int c = tid & 63;
            const int q = tid >> 6;
            const float4* pr = reinterpret_cast<const float4*>(&cb_re[(size_t)(k0 + c) * DIM + q * 16]);
            const float4* pi = reinterpret_cast<const float4*>(&cb_im[(size_t)(k0 + c) * DIM + q * 16]);
#pragma unroll
            for (int j = 0; j < 4; ++j) {
                float4 vr = pr[j];
                float4 vi = pi[j];
                int d = q * 16 + j * 4;
                csr[d + 0][c] = vr.x; csr[d + 1][c] = vr.y; csr[d + 2][c] = vr.z; csr[d + 3][c] = vr.w;
                csi[d + 0][c] = vi.x; csi[d + 1][c] = vi.y; csi[d + 2][c] = vi.z; csi[d + 3][c] = vi.w;
            }
        }
        __syncthreads();

        float accr[4][4], acci[4][4];
#pragma unroll
        for (int i = 0; i < 4; ++i)
#pragma unroll
            for (int j = 0; j < 4; ++j) { accr[i][j] = 0.0f; acci[i][j] = 0.0f; }

#pragma unroll 4
        for (int d = 0; d < DIM; ++d) {
            float4 xr = *reinterpret_cast<const float4*>(&xsr[d][ty * 4]);
            float4 xi = *reinterpret_cast<const float4*>(&xsi[d][ty * 4]);
            float4 cr = *reinterpret_cast<const float4*>(&csr[d][tx * 4]);
            float4 ci = *reinterpret_cast<const float4*>(&csi[d][tx * 4]);
            const float xrv[4] = {xr.x, xr.y, xr.z, xr.w};
            const float xiv[4] = {xi.x, xi.y, xi.z, xi.w};
            const float crv[4] = {cr.x, cr.y, cr.z, cr.w};
            const float civ[4] = {ci.x, ci.y, ci.z, ci.w};
#pragma unroll
            for (int i = 0; i < 4; ++i) {
#pragma unroll
                for (int j = 0; j < 4; ++j) {
                    accr[i][j] = fmaf(xrv[i], crv[j], accr[i][j]);
                    accr[i][j] = fmaf(xiv[i], civ[j], accr[i][j]);
                    acci[i][j] = fmaf(xrv[i], civ[j], acci[i][j]);
                    acci[i][j] = fmaf(-xiv[i], crv[j], acci[i][j]);
                }
            }
        }

        // ---- update per-thread running argmax (on mag^2; k ascending per thread) ----
#pragma unroll
        for (int i = 0; i < 4; ++i) {
#pragma unroll
            for (int j = 0; j < 4; ++j) {
                float m2 = accr[i][j] * accr[i][j] + acci[i][j] * acci[i][j];
                int k = k0 + tx * 4 + j;
                if (m2 > best_m[i]) { best_m[i] = m2; best_i[i] = k; }
            }
        }
    }

    // ---- reduce across the 16 tx lanes (same ty), tie-break lower index ----
#pragma unroll
    for (int m = 1; m < 16; m <<= 1) {
#pragma unroll
        for (int i = 0; i < 4; ++i) {
            float om = __shfl_xor(best_m[i], m, 64);
            int   oi = __shfl_xor(best_i[i], m, 64);
            if (om > best_m[i] || (om == best_m[i] && oi < best_i[i])) {
                best_m[i] = om; best_i[i] = oi;
            }
        }
    }
    if (tx == 0) {
#pragma unroll
        for (int i = 0; i < 4; ++i) {
            int n = row0 + ty * 4 + i;
            ws_mag[(size_t)kseg * NROWS + n] = best_m[i];
            ws_idx[(size_t)kseg * NROWS + n] = best_i[i];
        }
    }
}

__global__ __launch_bounds__(256) void reduce_gather(
    const float* __restrict__ ws_mag, const int* __restrict__ ws_idx,
    const float* __restrict__ cb_re, const float* __restrict__ cb_im,
    float* __restrict__ out)
{
    const int wave = threadIdx.x >> 6;
    const int lane = threadIdx.x & 63;
    const int n = blockIdx.x * 4 + wave;
    if (n >= NROWS) return;

    // all 64 lanes redundantly combine the KSPLIT partials (broadcast loads)
    float bm = -1.0f;
    int   bi = 0;
#pragma unroll
    for (int s = 0; s < KSPLIT; ++s) {
        float m = ws_mag[(size_t)s * NROWS + n];
        int   i = ws_idx[(size_t)s * NROWS + n];
        if (m > bm || (m == bm && i < bi)) { bm = m; bi = i; }
    }

    if (lane == 0) out[n] = (float)bi;  // index written as float (buffer dtype f32)

    float re = cb_re[(size_t)bi * DIM + lane];
    float im = cb_im[(size_t)bi * DIM + lane];
    float2* ro = reinterpret_cast<float2*>(out + NROWS);
    ro[(size_t)n * DIM + lane] = make_float2(re, im);
}

extern "C" void kernel_launch(void* const* d_in, const int* in_sizes, int n_in,
                              void* d_out, int out_size, void* d_ws, size_t ws_size,
                              hipStream_t stream)
{
    const float* x_re  = (const float*)d_in[0];
    const float* x_im  = (const float*)d_in[1];
    const float* cb_re = (const float*)d_in[2];
    const float* cb_im = (const float*)d_in[3];
    float* out = (float*)d_out;

    float* ws_mag = (float*)d_ws;
    int*   ws_idx = (int*)((char*)d_ws + sizeof(float) * (size_t)NROWS * KSPLIT);

    dim3 gridA(NROWS / BM, KSPLIT);
    quant_partial<<<gridA, 256, 0, stream>>>(x_re, x_im, cb_re, cb_im, ws_mag, ws_idx);
    reduce_gather<<<NROWS / 4, 256, 0, stream>>>(ws_mag, ws_idx, cb_re, cb_im, out);
}

// Round 2
// 367.531 us; speedup vs baseline: 4.9976x; 4.9976x over previous
//
#include <hip/hip_runtime.h>

#define NROWS 16384
#define KCB   16384
#define DD    64
#define BM    256
#define BN    64
#define CSPLIT 16
#define COLS_PER_BLOCK (KCB / CSPLIT)   // 1024
#define NCT (COLS_PER_BLOCK / BN)       // 16 col-tiles per block
#define CAP 1024
#define DELTA 0.45f

typedef __attribute__((ext_vector_type(8))) short bf16x8;
typedef __attribute__((ext_vector_type(4))) float f32x4;

__device__ __forceinline__ unsigned pk_bf16(float lo, float hi) {
    unsigned a = __float_as_uint(lo);
    unsigned b = __float_as_uint(hi);
    a += 0x7FFFu + ((a >> 16) & 1u);   // RNE to bf16
    b += 0x7FFFu + ((b >> 16) & 1u);
    return (a >> 16) | (b & 0xFFFF0000u);
}

// XOR swizzle within 128B rows: 2-way max bank aliasing on ds_read_b128
__device__ __forceinline__ unsigned swz(unsigned row, unsigned byte_in_row) {
    return row * 128u + (byte_in_row ^ ((row & 7u) << 4));
}

template<int PASS>
__global__ __launch_bounds__(512, 2) void score_kernel(
    const float* __restrict__ x_re, const float* __restrict__ x_im,
    const float* __restrict__ cb_re, const float* __restrict__ cb_im,
    unsigned* __restrict__ row_max_bits,
    unsigned long long* __restrict__ best_packed)
{
    __shared__ unsigned short Are[BM * DD];        // 32 KB
    __shared__ unsigned short Aim[BM * DD];        // 32 KB
    __shared__ unsigned short Bre[2][BN * DD];     // 16 KB
    __shared__ unsigned short Bim[2][BN * DD];     // 16 KB
    __shared__ unsigned cand[CAP];                 // 4 KB
    __shared__ int cand_cnt;

    const int tid  = threadIdx.x;
    const int lane = tid & 63;
    const int wid  = tid >> 6;          // 0..7
    const int row0 = blockIdx.x * BM;
    const int col0 = blockIdx.y * COLS_PER_BLOCK;
    const int wr0  = (wid >> 1) * 64;   // wave row origin (4 groups)
    const int wc0  = (wid & 1) * 32;    // wave col origin (2 groups)
    const int l15  = lane & 15;
    const int lhi  = lane >> 4;         // 0..3

    char* AreB = (char*)Are;
    char* AimB = (char*)Aim;

    if (tid == 0) cand_cnt = 0;

    // ---- stage A tile (256 rows x 64 d, re+im) fp32 -> bf16, swizzled ----
    {
        const int r  = tid >> 1;
        const int d0 = (tid & 1) * 32;
        const float4* pr = (const float4*)(x_re + (size_t)(row0 + r) * DD + d0);
        const float4* pi = (const float4*)(x_im + (size_t)(row0 + r) * DD + d0);
        float4 vr[8], vi[8];
#pragma unroll
        for (int j = 0; j < 8; ++j) { vr[j] = pr[j]; vi[j] = pi[j]; }
#pragma unroll
        for (int j = 0; j < 4; ++j) {
            uint4 wr, wi;
            wr.x = pk_bf16(vr[2*j].x, vr[2*j].y);   wr.y = pk_bf16(vr[2*j].z, vr[2*j].w);
            wr.z = pk_bf16(vr[2*j+1].x, vr[2*j+1].y); wr.w = pk_bf16(vr[2*j+1].z, vr[2*j+1].w);
            wi.x = pk_bf16(vi[2*j].x, vi[2*j].y);   wi.y = pk_bf16(vi[2*j].z, vi[2*j].w);
            wi.z = pk_bf16(vi[2*j+1].x, vi[2*j+1].y); wi.w = pk_bf16(vi[2*j+1].z, vi[2*j+1].w);
            unsigned off = swz(r, (d0 + 8*j) * 2);
            *(uint4*)(AreB + off) = wr;
            *(uint4*)(AimB + off) = wi;
        }
    }

    // per-lane threshold / running-max state
    float rm[4][4];     // pass1: running max of m2, indexed [ar][reg]
    float thr[4][4];    // pass2: filter threshold
#pragma unroll
    for (int a = 0; a < 4; ++a)
#pragma unroll
        for (int r = 0; r < 4; ++r) rm[a][r] = 0.0f;
    if (PASS == 2) {
#pragma unroll
        for (int a = 0; a < 4; ++a)
#pragma unroll
            for (int r = 0; r < 4; ++r) {
                int n = row0 + wr0 + a * 16 + lhi * 4 + r;
                float mx = __uint_as_float(row_max_bits[n]);
                float tm = sqrtf(mx) - DELTA;
                thr[a][r] = (tm > 0.0f) ? tm * tm : -1.0f;
            }
    }

    // ---- B staging helpers (reg-staged, issue-early / write-late) ----
    const int bc = tid >> 3;            // 0..63 col within tile
    const int bo = (tid & 7) * 8;       // 0..56 d offset
    float4 sr0, sr1, si0, si1;

    auto stage_load = [&](int t) {
        int k = col0 + t * BN + bc;
        const float4* gr = (const float4*)(cb_re + (size_t)k * DD + bo);
        const float4* gi = (const float4*)(cb_im + (size_t)k * DD + bo);
        sr0 = gr[0]; sr1 = gr[1];
        si0 = gi[0]; si1 = gi[1];
    };
    auto stage_write = [&](int buf) {
        uint4 wr, wi;
        wr.x = pk_bf16(sr0.x, sr0.y); wr.y = pk_bf16(sr0.z, sr0.w);
        wr.z = pk_bf16(sr1.x, sr1.y); wr.w = pk_bf16(sr1.z, sr1.w);
        wi.x = pk_bf16(si0.x, si0.y); wi.y = pk_bf16(si0.z, si0.w);
        wi.z = pk_bf16(si1.x, si1.y); wi.w = pk_bf16(si1.z, si1.w);
        unsigned off = swz(bc, bo * 2);
        *(uint4*)((char*)Bre[buf] + off) = wr;
        *(uint4*)((char*)Bim[buf] + off) = wi;
    };

    stage_load(0);
    stage_write(0);
    __syncthreads();

    for (int t = 0; t < NCT; ++t) {
        const int cur = t & 1;
        if (t + 1 < NCT) stage_load(t + 1);   // HBM latency hides under MFMA

        f32x4 accre[4][2], accim[4][2];
#pragma unroll
        for (int a = 0; a < 4; ++a)
#pragma unroll
            for (int b = 0; b < 2; ++b) {
                accre[a][b] = (f32x4){0.f, 0.f, 0.f, 0.f};
                accim[a][b] = (f32x4){0.f, 0.f, 0.f, 0.f};
            }

#pragma unroll
        for (int ks = 0; ks < 2; ++ks) {
            const unsigned byte = ks * 64 + lhi * 16;
            bf16x8 ar[4], ai[4], br[2], bi[2];
#pragma unroll
            for (int a = 0; a < 4; ++a) {
                unsigned off = swz(wr0 + a * 16 + l15, byte);
                ar[a] = *(const bf16x8*)(AreB + off);
                ai[a] = *(const bf16x8*)(AimB + off);
            }
#pragma unroll
            for (int b = 0; b < 2; ++b) {
                unsigned off = swz(wc0 + b * 16 + l15, byte);
                br[b] = *(const bf16x8*)((const char*)Bre[cur] + off);
                bi[b] = *(const bf16x8*)((const char*)Bim[cur] + off);
            }
#pragma unroll
            for (int a = 0; a < 4; ++a)
#pragma unroll
                for (int b = 0; b < 2; ++b) {
                    accre[a][b] = __builtin_amdgcn_mfma_f32_16x16x32_bf16(ar[a], br[b], accre[a][b], 0, 0, 0);
                    accre[a][b] = __builtin_amdgcn_mfma_f32_16x16x32_bf16(ai[a], bi[b], accre[a][b], 0, 0, 0);
                    accim[a][b] = __builtin_amdgcn_mfma_f32_16x16x32_bf16(ar[a], bi[b], accim[a][b], 0, 0, 0);
                }
            // negate x_im fragments in-register (bf16 sign-bit flip), then -xim*cre
#pragma unroll
            for (int a = 0; a < 4; ++a) ai[a] = ai[a] ^ (short)0x8000;
#pragma unroll
            for (int a = 0; a < 4; ++a)
#pragma unroll
                for (int b = 0; b < 2; ++b)
                    accim[a][b] = __builtin_amdgcn_mfma_f32_16x16x32_bf16(ai[a], br[b], accim[a][b], 0, 0, 0);
        }

        // ---- epilogue ----
        if (PASS == 1) {
#pragma unroll
            for (int a = 0; a < 4; ++a)
#pragma unroll
                for (int b = 0; b < 2; ++b)
#pragma unroll
                    for (int r = 0; r < 4; ++r) {
                        float re = accre[a][b][r], im = accim[a][b][r];
                        float m2 = re * re + im * im;
                        rm[a][r] = fmaxf(rm[a][r], m2);
                    }
        } else {
#pragma unroll
            for (int a = 0; a < 4; ++a)
#pragma unroll
                for (int b = 0; b < 2; ++b)
#pragma unroll
                    for (int r = 0; r < 4; ++r) {
                        float re = accre[a][b][r], im = accim[a][b][r];
                        float m2 = re * re + im * im;
                        if (m2 >= thr[a][r]) {
                            int n = row0 + wr0 + a * 16 + lhi * 4 + r;
                            int k = col0 + t * BN + wc0 + b * 16 + l15;
                            int idx = atomicAdd(&cand_cnt, 1);
                            if (idx < CAP) cand[idx] = ((unsigned)n << 14) | (unsigned)k;
                        }
                    }
        }

        if (t + 1 < NCT) stage_write(1 - cur);
        __syncthreads();
    }

    if (PASS == 1) {
        // reduce per-row max across the 16 column lanes, then atomicMax
#pragma unroll
        for (int m = 1; m < 16; m <<= 1)
#pragma unroll
            for (int a = 0; a < 4; ++a)
#pragma unroll
                for (int r = 0; r < 4; ++r)
                    rm[a][r] = fmaxf(rm[a][r], __shfl_xor(rm[a][r], m, 64));
        if (l15 == 0) {
#pragma unroll
            for (int a = 0; a < 4; ++a)
#pragma unroll
                for (int r = 0; r < 4; ++r) {
                    int n = row0 + wr0 + a * 16 + lhi * 4 + r;
                    atomicMax(&row_max_bits[n], __float_as_uint(rm[a][r]));
                }
        }
    } else {
        // exact fp32 rescore of candidates (replicates round-1 FMA order)
        int cnt = cand_cnt < CAP ? cand_cnt : CAP;
        for (int i = tid; i < cnt; i += 512) {
            unsigned e = cand[i];
            int n = (int)(e >> 14);
            int k = (int)(e & 16383u);
            const float* xr = x_re + (size_t)n * DD;
            const float* xi = x_im + (size_t)n * DD;
            const float* cr = cb_re + (size_t)k * DD;
            const float* ci = cb_im + (size_t)k * DD;
            float accr = 0.0f, acci = 0.0f;
            for (int d = 0; d < DD; ++d) {
                float xrv = xr[d], xiv = xi[d], crv = cr[d], civ = ci[d];
                accr = fmaf(xrv, crv, accr);
                accr = fmaf(xiv, civ, accr);
                acci = fmaf(xrv, civ, acci);
                acci = fmaf(-xiv, crv, acci);
            }
            float m2 = accr * accr + acci * acci;
            unsigned long long key =
                ((unsigned long long)__float_as_uint(m2) << 32) | (unsigned)(~(unsigned)k);
            atomicMax(&best_packed[n], key);
        }
    }
}

__global__ __launch_bounds__(256) void init_ws(unsigned* row_max_bits,
                                               unsigned long long* best_packed)
{
    int i = blockIdx.x * 256 + threadIdx.x;
    if (i < NROWS) { row_max_bits[i] = 0u; best_packed[i] = 0ull; }
}

__global__ __launch_bounds__(256) void finalize(
    const unsigned long long* __restrict__ best_packed,
    const float* __restrict__ cb_re, const float* __restrict__ cb_im,
    float* __restrict__ out)
{
    const int wave = threadIdx.x >> 6;
    const int lane = threadIdx.x & 63;
    const int n = blockIdx.x * 4 + wave;
    if (n >= NROWS) return;

    unsigned long long p = best_packed[n];
    unsigned k = ~(unsigned)(p & 0xFFFFFFFFull);

    if (lane == 0) out[n] = (float)k;

    float re = cb_re[(size_t)k * DD + lane];
    float im = cb_im[(size_t)k * DD + lane];
    float2* ro = reinterpret_cast<float2*>(out + NROWS);
    ro[(size_t)n * DD + lane] = make_float2(re, im);
}

extern "C" void kernel_launch(void* const* d_in, const int* in_sizes, int n_in,
                              void* d_out, int out_size, void* d_ws, size_t ws_size,
                              hipStream_t stream)
{
    const float* x_re  = (const float*)d_in[0];
    const float* x_im  = (const float*)d_in[1];
    const float* cb_re = (const float*)d_in[2];
    const float* cb_im = (const float*)d_in[3];
    float* out = (float*)d_out;

    unsigned* row_max_bits = (unsigned*)d_ws;                            // 64 KB
    unsigned long long* best_packed =
        (unsigned long long*)((char*)d_ws + sizeof(unsigned) * NROWS);   // 128 KB

    init_ws<<<NROWS / 256, 256, 0, stream>>>(row_max_bits, best_packed);

    dim3 grid(NROWS / BM, CSPLIT);
    score_kernel<1><<<grid, 512, 0, stream>>>(x_re, x_im, cb_re, cb_im,
                                              row_max_bits, best_packed);
    score_kernel<2><<<grid, 512, 0, stream>>>(x_re, x_im, cb_re, cb_im,
                                              row_max_bits, best_packed);

    finalize<<<NROWS / 4, 256, 0, stream>>>(best_packed, cb_re, cb_im, out);
}